// Round 17
// baseline (580.594 us; speedup 1.0000x reference)
//
#include <hip/hip_runtime.h>

#define HH 64
#define WW 64
#define HW 4096
#define CC 256
#define BB 4
#define GG 4
#define NPAIR 3

typedef __attribute__((ext_vector_type(8))) short short8;
typedef __attribute__((ext_vector_type(4))) float f32x4;
typedef unsigned short ushort_t;

__device__ inline ushort_t f2bf(float x) {
    unsigned int u = __float_as_uint(x);
    unsigned int r = (u + 0x7fffu + ((u >> 16) & 1u)) >> 16;
    return (ushort_t)r;
}
__device__ inline float bflo(unsigned u) { return __uint_as_float(u << 16); }
__device__ inline float bfhi(unsigned u) { return __uint_as_float(u & 0xffff0000u); }

// ---------------- merged weight prep (wdef | woff | wfus) ----------------
__global__ void prep_all(const float* __restrict__ wd, const float* __restrict__ wo,
                         const float* __restrict__ wf, ushort_t* __restrict__ wdefMF,
                         ushort_t* __restrict__ woffMF, ushort_t* __restrict__ wfusMF) {
    int idx = blockIdx.x * 256 + threadIdx.x;
    if (idx < 589824) {  // wdef -> wdefMF[k][o][c]
        int k = idx >> 16;
        int rem = idx & 65535;
        int o = rem >> 8;
        int c = rem & 255;
        wdefMF[idx] = f2bf(wd[((size_t)(o * 256 + c)) * 9 + k]);
        return;
    }
    idx -= 589824;
    if (idx < 230400) {  // woff -> woffMF[k][80][320] zero-padded
        int k = idx / (80 * 320);
        int rem = idx % (80 * 320);
        int o = rem / 320;
        int ci = rem % 320;
        woffMF[idx] = (o < 72 && ci < 305) ? f2bf(wo[((size_t)o * 305 + ci) * 9 + k])
                                           : (ushort_t)0;
        return;
    }
    idx -= 230400;
    if (idx < 2359296) {  // wfus -> wfusMF[k][o][ci]
        int k = idx / (256 * 1024);
        int rem = idx % (256 * 1024);
        int o = rem / 1024;
        int ci = rem % 1024;
        wfusMF[idx] = f2bf(wf[((size_t)o * 1024 + ci) * 9 + k]);
    }
}

// ---------------- XT build ----------------
__global__ void __launch_bounds__(256) xt_build(const float* __restrict__ in,
                                                ushort_t* __restrict__ XT) {
    __shared__ ushort_t tileT[64][72];
    int hw0 = blockIdx.x * 64;
    int ct = blockIdx.y;
    int z = blockIdx.z;
    int pair = z >> 2, b = z & 3;
    int t = threadIdx.x;
    int cil = t >> 2, q = t & 3;
    const float* sp = in + ((size_t)(b * 4 + pair) * 256 + ct * 64 + cil) * HW + hw0 + q * 16;
#pragma unroll
    for (int i = 0; i < 16; ++i) tileT[q * 16 + i][cil] = f2bf(sp[i]);
    __syncthreads();
    int hwl = t >> 2;
    const uint4* tp = reinterpret_cast<const uint4*>(&tileT[hwl][q * 16]);
    uint4* op = reinterpret_cast<uint4*>(
        &XT[((size_t)z * HW + hw0 + hwl) * 320 + ct * 64 + q * 16]);
    op[0] = tp[0];
    op[1] = tp[1];
}

// ---------------- correlation partials ----------------
__global__ void __launch_bounds__(256, 8) corr_partial(const float* __restrict__ in,
                                                       float* __restrict__ P) {
    __shared__ float x1l[8][64];
    __shared__ float x2l[8][7][76];
    int h = blockIdx.x, z = blockIdx.y, cg = blockIdx.z;
    int pair = z >> 2, b = z & 3;
    const float* x1 = in + (size_t)(b * GG + pair) * CC * HW + h * WW;
    const float* x2 = in + (size_t)(b * GG + 3) * CC * HW;
    int tid = threadIdx.x;
    int w = tid & 63;
    int dg = tid >> 6;

    float acc[2][7];
#pragma unroll
    for (int i = 0; i < 2; ++i)
#pragma unroll
        for (int j = 0; j < 7; ++j) acc[i][j] = 0.f;

    for (int c0 = cg * 64; c0 < cg * 64 + 64; c0 += 8) {
        __syncthreads();
#pragma unroll
        for (int idx = tid; idx < 512; idx += 256) {
            int cc = idx >> 6, ww = idx & 63;
            x1l[cc][ww] = x1[(size_t)(c0 + cc) * HW + ww];
        }
        for (int idx = tid; idx < 8 * 7 * 76; idx += 256) {
            int cc = idx / 532;
            int rem = idx - cc * 532;
            int r = rem / 76;
            int cl = rem - r * 76;
            int row = h + 2 * (r - 3);
            int col = cl - 6;
            float v = 0.f;
            if (row >= 0 && row < HH && col >= 0 && col < WW)
                v = x2[(size_t)(c0 + cc) * HW + row * WW + col];
            x2l[cc][r][cl] = v;
        }
        __syncthreads();
#pragma unroll
        for (int cc = 0; cc < 8; ++cc) {
            float x1v = x1l[cc][w];
#pragma unroll
            for (int i = 0; i < 2; ++i) {
                int di = dg * 2 + i;
                if (di < 7) {
#pragma unroll
                    for (int dj = 0; dj < 7; ++dj)
                        acc[i][dj] += x1v * x2l[cc][di][w + 2 * dj];
                }
            }
        }
    }
    float* pp = P + ((size_t)(cg * 12 + z) * 49) * HW + h * WW + w;
#pragma unroll
    for (int i = 0; i < 2; ++i) {
        int di = dg * 2 + i;
        if (di < 7) {
#pragma unroll
            for (int dj = 0; dj < 7; ++dj)
                pp[(size_t)(di * 7 + dj) * HW] = acc[i][dj];
        }
    }
}

// ---------------- corr reduce ----------------
__global__ void __launch_bounds__(256) corr_reduce(const float* __restrict__ P,
                                                   ushort_t* __restrict__ XT) {
    int h = blockIdx.x, z = blockIdx.y;
    int tid = threadIdx.x;
    int w = tid & 63;
    int dg = tid >> 6;
    const size_t cgs = (size_t)12 * 49 * HW;
    ushort_t* xrow = XT + ((size_t)z * HW + h * WW + w) * 320;
#pragma unroll
    for (int i = 0; i < 2; ++i) {
        int di = dg * 2 + i;
        if (di < 7) {
#pragma unroll
            for (int dj = 0; dj < 7; ++dj) {
                int d = di * 7 + dj;
                const float* pp = P + ((size_t)z * 49 + d) * HW + h * WW + w;
                float s = pp[0] + pp[cgs] + pp[2 * cgs] + pp[3 * cgs];
                xrow[256 + d] = f2bf(s * (1.f / 256.f));
            }
        }
    }
    if (dg == 3) {
#pragma unroll
        for (int p = 0; p < 15; ++p) xrow[305 + p] = 0;
    }
}

// ---------------- offset conv via MFMA bf16 (r14 best, unchanged) ----------------
__global__ void __launch_bounds__(256, 2) offconv_mfma(const ushort_t* __restrict__ XT,
                                                       const ushort_t* __restrict__ wmf,
                                                       float* __restrict__ off) {
    __shared__ ushort_t a_lds[9][80][40];
    __shared__ ushort_t b_hal[264][40];
    int lin = (blockIdx.x & 7) * 48 + (blockIdx.x >> 3);
    int z = lin >> 5;
    int n0t = lin & 31;
    int h0 = n0t * 2;
    int t = threadIdx.x;
    int wid = t >> 6;
    int lane = t & 63;
    int l15 = lane & 15;
    int kq = lane >> 4;
    const ushort_t* xtb = XT + (size_t)z * HW * 320;

    f32x4 acc[5][2];
#pragma unroll
    for (int m = 0; m < 5; ++m)
#pragma unroll
        for (int n = 0; n < 2; ++n) acc[m][n] = (f32x4){0.f, 0.f, 0.f, 0.f};

#pragma unroll 1
    for (int cs = 0; cs < 10; ++cs) {
        int ci0 = cs * 32;
        __syncthreads();
        for (int idx = t; idx < 264; idx += 256) {
            int r = idx / 66, c = idx - r * 66;
            int hP = h0 + r - 1, wP = c - 1;
            uint4* dst = reinterpret_cast<uint4*>(&b_hal[idx][0]);
            if (hP >= 0 && hP < HH && wP >= 0 && wP < WW) {
                const uint4* src = reinterpret_cast<const uint4*>(
                    xtb + (size_t)(hP * WW + wP) * 320 + ci0);
                dst[0] = src[0];
                dst[1] = src[1];
                dst[2] = src[2];
                dst[3] = src[3];
            } else {
                uint4 zz = make_uint4(0, 0, 0, 0);
                dst[0] = zz;
                dst[1] = zz;
                dst[2] = zz;
                dst[3] = zz;
            }
        }
        for (int idx = t; idx < 2880; idx += 256) {
            int tp = idx / 320;
            int rem = idx - tp * 320;
            int o = rem >> 2, q = rem & 3;
            *reinterpret_cast<uint4*>(&a_lds[tp][o][q * 8]) =
                *reinterpret_cast<const uint4*>(
                    wmf + ((size_t)tp * 80 + o) * 320 + ci0 + q * 8);
        }
        __syncthreads();
#pragma unroll 1
        for (int tap = 0; tap < 9; ++tap) {
            int kh = tap / 3, kw = tap - kh * 3;
            short8 af[5], bf[2];
#pragma unroll
            for (int m = 0; m < 5; ++m)
                af[m] = *reinterpret_cast<const short8*>(&a_lds[tap][m * 16 + l15][kq * 8]);
#pragma unroll
            for (int n = 0; n < 2; ++n) {
                int p = wid * 32 + n * 16 + l15;
                int pos = ((p >> 6) + kh) * 66 + (p & 63) + kw;
                bf[n] = *reinterpret_cast<const short8*>(&b_hal[pos][kq * 8]);
            }
#pragma unroll
            for (int m = 0; m < 5; ++m)
#pragma unroll
                for (int n = 0; n < 2; ++n)
                    acc[m][n] = __builtin_amdgcn_mfma_f32_16x16x32_bf16(af[m], bf[n],
                                                                        acc[m][n], 0, 0, 0);
        }
    }
    float* ob = off + (size_t)z * 72 * HW + h0 * 64 + wid * 32;
#pragma unroll
    for (int m = 0; m < 5; ++m)
#pragma unroll
        for (int n = 0; n < 2; ++n)
#pragma unroll
            for (int e = 0; e < 4; ++e) {
                int o_l = m * 16 + kq * 4 + e;
                if (o_l < 72) ob[(size_t)o_l * HW + n * 16 + l15] = acc[m][n][e];
            }
}

// ---------------- deformable conv via MFMA bf16 (r10 optimum, verbatim) ----------------
__global__ void __launch_bounds__(256, 3) deform_mfma(const ushort_t* __restrict__ XT,
                                                      const float* __restrict__ off,
                                                      const ushort_t* __restrict__ wmf,
                                                      ushort_t* __restrict__ FT) {
    __shared__ ushort_t b_lds[64][264];
    int u = blockIdx.x & 7, v = blockIdx.x >> 3;
    int lin = u * 96 + v;
    int z = lin >> 6, h = lin & 63;
    int b = z & 3, pair = z >> 2;

    const ushort_t* xtz = XT + (size_t)z * HW * 320;
    const float* offp = off + (size_t)z * 72 * HW;
    int tid = threadIdx.x;
    int lane = tid & 63;
    int g = tid >> 6;
    int l15 = tid & 15;
    int kq = (tid >> 4) & 3;

    f32x4 acc[4][4];
#pragma unroll
    for (int m = 0; m < 4; ++m)
#pragma unroll
        for (int n = 0; n < 4; ++n) acc[m][n] = (f32x4){0.f, 0.f, 0.f, 0.f};

    for (int k = 0; k < 9; ++k) {
        __syncthreads();
        {
            float oy = offp[(size_t)(g * 18 + k * 2 + 0) * HW + h * WW + lane];
            float ox = offp[(size_t)(g * 18 + k * 2 + 1) * HW + h * WW + lane];
            float py = (float)h + (float)(k / 3 - 1) + oy;
            float px = (float)lane + (float)(k % 3 - 1) + ox;
            float y0f = floorf(py), x0f = floorf(px);
            float fy = py - y0f, fx = px - x0f;
            int y0 = (int)y0f, x0 = (int)x0f;
            int y1 = y0 + 1, x1 = x0 + 1;
            bool vy0 = (y0 >= 0) && (y0 < HH);
            bool vy1 = (y1 >= 0) && (y1 < HH);
            bool vx0 = (x0 >= 0) && (x0 < WW);
            bool vx1 = (x1 >= 0) && (x1 < WW);
            float w00 = (1.f - fy) * (1.f - fx) * ((vy0 && vx0) ? 1.f : 0.f);
            float w01 = (1.f - fy) * fx * ((vy0 && vx1) ? 1.f : 0.f);
            float w10 = fy * (1.f - fx) * ((vy1 && vx0) ? 1.f : 0.f);
            float w11 = fy * fx * ((vy1 && vx1) ? 1.f : 0.f);
            int cy0 = min(max(y0, 0), HH - 1), cy1 = min(max(y1, 0), HH - 1);
            int cx0 = min(max(x0, 0), WW - 1), cx1 = min(max(x1, 0), WW - 1);
            const ushort_t* p00 = xtz + (size_t)(cy0 * WW + cx0) * 320 + g * 64;
            const ushort_t* p01 = xtz + (size_t)(cy0 * WW + cx1) * 320 + g * 64;
            const ushort_t* p10 = xtz + (size_t)(cy1 * WW + cx0) * 320 + g * 64;
            const ushort_t* p11 = xtz + (size_t)(cy1 * WW + cx1) * 320 + g * 64;
#pragma unroll
            for (int c0 = 0; c0 < 64; c0 += 8) {
                uint4 a00 = *reinterpret_cast<const uint4*>(p00 + c0);
                uint4 a01 = *reinterpret_cast<const uint4*>(p01 + c0);
                uint4 a10 = *reinterpret_cast<const uint4*>(p10 + c0);
                uint4 a11 = *reinterpret_cast<const uint4*>(p11 + c0);
                unsigned pw[4];
                const unsigned* u00 = &a00.x;
                const unsigned* u01 = &a01.x;
                const unsigned* u10 = &a10.x;
                const unsigned* u11 = &a11.x;
#pragma unroll
                for (int q = 0; q < 4; ++q) {
                    float s0 = w00 * bflo(u00[q]) + w01 * bflo(u01[q]) +
                               w10 * bflo(u10[q]) + w11 * bflo(u11[q]);
                    float s1 = w00 * bfhi(u00[q]) + w01 * bfhi(u01[q]) +
                               w10 * bfhi(u10[q]) + w11 * bfhi(u11[q]);
                    pw[q] = (unsigned)f2bf(s0) | ((unsigned)f2bf(s1) << 16);
                }
                *reinterpret_cast<uint4*>(&b_lds[lane][g * 64 + c0]) =
                    make_uint4(pw[0], pw[1], pw[2], pw[3]);
            }
        }
        __syncthreads();
        const ushort_t* wkbase = wmf + (size_t)k * 65536 + (size_t)(g * 64) * 256;
#pragma unroll 1
        for (int cs = 0; cs < 8; ++cs) {
            int c0 = cs * 32;
            short8 bfr[4], afr[4];
#pragma unroll
            for (int n = 0; n < 4; ++n)
                bfr[n] = *reinterpret_cast<const short8*>(&b_lds[n * 16 + l15][c0 + kq * 8]);
#pragma unroll
            for (int m = 0; m < 4; ++m)
                afr[m] = *reinterpret_cast<const short8*>(
                    wkbase + (size_t)(m * 16 + l15) * 256 + c0 + kq * 8);
#pragma unroll
            for (int m = 0; m < 4; ++m)
#pragma unroll
                for (int n = 0; n < 4; ++n)
                    acc[m][n] = __builtin_amdgcn_mfma_f32_16x16x32_bf16(afr[m], bfr[n],
                                                                        acc[m][n], 0, 0, 0);
        }
    }
    __syncthreads();
#pragma unroll
    for (int m = 0; m < 4; ++m)
#pragma unroll
        for (int n = 0; n < 4; ++n) {
            unsigned lo = (unsigned)f2bf(acc[m][n][0]) | ((unsigned)f2bf(acc[m][n][1]) << 16);
            unsigned hi = (unsigned)f2bf(acc[m][n][2]) | ((unsigned)f2bf(acc[m][n][3]) << 16);
            uint2 vv = make_uint2(lo, hi);
            *reinterpret_cast<uint2*>(&b_lds[n * 16 + l15][g * 64 + m * 16 + kq * 4]) = vv;
        }
    __syncthreads();
    int wout = tid >> 2, ch = tid & 3;
    ushort_t* dst = FT + ((size_t)b * HW + h * 64 + wout) * 1024 + pair * 256 + ch * 64;
    const ushort_t* srcl = &b_lds[wout][ch * 64];
#pragma unroll
    for (int i = 0; i < 8; ++i) {
        uint4 vv = *reinterpret_cast<const uint4*>(srcl + i * 8);
        *reinterpret_cast<uint4*>(dst + i * 8) = vv;
    }
}

// ---------------- FT build (y part) ----------------
__global__ void __launch_bounds__(256) ft_build_y(const float* __restrict__ in,
                                                  ushort_t* __restrict__ FT) {
    __shared__ ushort_t tileT[64][72];
    int hw0 = blockIdx.x * 64;
    int ct = blockIdx.y;
    int b = blockIdx.z;
    int t = threadIdx.x;
    int cil = t >> 2, q = t & 3;
    const float* sp = in + ((size_t)(b * 4 + 3) * 256 + ct * 64 + cil) * HW + hw0 + q * 16;
#pragma unroll
    for (int i = 0; i < 16; ++i) tileT[q * 16 + i][cil] = f2bf(sp[i]);
    __syncthreads();
    int hwl = t >> 2;
    const uint4* tp = reinterpret_cast<const uint4*>(&tileT[hwl][q * 16]);
    uint4* op = reinterpret_cast<uint4*>(
        &FT[((size_t)b * HW + hw0 + hwl) * 1024 + 768 + ct * 64 + q * 16]);
    op[0] = tp[0];
    op[1] = tp[1];
}

// ---------------- fusion conv via MFMA bf16 (64o x 256hw tile, halo-staged) ----------------
// grid 256 = 8 XCD x 32; lin = (bid&7)*32 + bid>>3; ot = lin&3 adjacent per (n,b).
// Per ci-chunk: B halo 6x66 pos + A [9][64] staged once, feeds 144 MFMAs (2x r14).
__global__ void __launch_bounds__(256, 2) fusion_mfma(const ushort_t* __restrict__ FT,
                                                      const ushort_t* __restrict__ wmf,
                                                      float* __restrict__ out) {
    __shared__ ushort_t a_lds[9][64][40];   // 46,080 B
    __shared__ ushort_t b_hal[396][40];     // 31,680 B  (6 rows x 66 cols)
    int lin = (blockIdx.x & 7) * 32 + (blockIdx.x >> 3);
    int ot = lin & 3;
    int g2 = lin >> 2;
    int n0t = g2 & 15;
    int b = g2 >> 4;
    int o0 = ot * 64;
    int h0 = n0t * 4;  // 4 h-rows = 256 hw
    int t = threadIdx.x;
    int wid = t >> 6;
    int lane = t & 63;
    int l15 = lane & 15;
    int kq = lane >> 4;
    const ushort_t* ftb = FT + (size_t)b * HW * 1024;

    f32x4 acc[4][4];
#pragma unroll
    for (int fm = 0; fm < 4; ++fm)
#pragma unroll
        for (int fn = 0; fn < 4; ++fn) acc[fm][fn] = (f32x4){0.f, 0.f, 0.f, 0.f};

#pragma unroll 1
    for (int cs = 0; cs < 32; ++cs) {
        int ci0 = cs * 32;
        __syncthreads();
        // stage B halo: 396 positions x 32 ci
        for (int idx = t; idx < 396; idx += 256) {
            int r = idx / 66, c = idx - r * 66;
            int hP = h0 + r - 1, wP = c - 1;
            uint4* dst = reinterpret_cast<uint4*>(&b_hal[idx][0]);
            if (hP >= 0 && hP < HH && wP >= 0 && wP < WW) {
                const uint4* src = reinterpret_cast<const uint4*>(
                    ftb + (size_t)(hP * WW + wP) * 1024 + ci0);
                dst[0] = src[0];
                dst[1] = src[1];
                dst[2] = src[2];
                dst[3] = src[3];
            } else {
                uint4 zz = make_uint4(0, 0, 0, 0);
                dst[0] = zz;
                dst[1] = zz;
                dst[2] = zz;
                dst[3] = zz;
            }
        }
        // stage A: 9 taps x 64 o x 32 ci
        for (int idx = t; idx < 2304; idx += 256) {
            int tp = idx >> 8;
            int rem = idx & 255;
            int o = rem >> 2, q = rem & 3;
            *reinterpret_cast<uint4*>(&a_lds[tp][o][q * 8]) =
                *reinterpret_cast<const uint4*>(
                    wmf + ((size_t)(tp * 256 + o0 + o) << 10) + ci0 + q * 8);
        }
        __syncthreads();
#pragma unroll 1
        for (int tap = 0; tap < 9; ++tap) {
            int kh = tap / 3, kw = tap - kh * 3;
            short8 af[4], bf[4];
#pragma unroll
            for (int m = 0; m < 4; ++m)
                af[m] = *reinterpret_cast<const short8*>(&a_lds[tap][m * 16 + l15][kq * 8]);
#pragma unroll
            for (int n = 0; n < 4; ++n) {
                int p = wid * 64 + n * 16 + l15;  // local hw 0..255
                int pos = ((p >> 6) + kh) * 66 + (p & 63) + kw;
                bf[n] = *reinterpret_cast<const short8*>(&b_hal[pos][kq * 8]);
            }
#pragma unroll
            for (int m = 0; m < 4; ++m)
#pragma unroll
                for (int n = 0; n < 4; ++n)
                    acc[m][n] = __builtin_amdgcn_mfma_f32_16x16x32_bf16(af[m], bf[n],
                                                                        acc[m][n], 0, 0, 0);
        }
    }
    float* ob = out + ((size_t)b * 256 + o0) * HW + h0 * 64 + wid * 64;
#pragma unroll
    for (int fm = 0; fm < 4; ++fm)
#pragma unroll
        for (int fn = 0; fn < 4; ++fn)
#pragma unroll
            for (int e = 0; e < 4; ++e) {
                int o_l = fm * 16 + 4 * kq + e;
                ob[(size_t)o_l * HW + fn * 16 + l15] = acc[fm][fn][e];
            }
}

extern "C" void kernel_launch(void* const* d_in, const int* in_sizes, int n_in,
                              void* d_out, int out_size, void* d_ws, size_t ws_size,
                              hipStream_t stream) {
    const float* in   = (const float*)d_in[0];   // [16,256,64,64]
    const float* wOff = (const float*)d_in[1];   // [72,305,3,3]
    const float* wDef = (const float*)d_in[2];   // [256,256,3,3]
    const float* wFus = (const float*)d_in[3];   // [256,1024,3,3]
    float* out = (float*)d_out;                  // [4,256,64,64]
    char* base = (char*)d_ws;

    ushort_t* XT     = (ushort_t*)base;                 // 31,457,280 B
    ushort_t* FT     = (ushort_t*)(base + 31457280);    // 33,554,432 B -> 65,011,712
    float* corrP     = (float*)(base + 31457280);       // 38,535,168 B (dead early)
    float* offB      = (float*)(base + 65011712);       // 14,155,776 B -> 79,167,488
    ushort_t* wdefMF = (ushort_t*)(base + 79167488);    //  1,179,648 B -> 80,347,136
    ushort_t* woffMF = (ushort_t*)(base + 80347136);    //    460,800 B -> 80,807,936
    ushort_t* wfusMF = (ushort_t*)(base + 80807936);    //  4,718,592 B -> 85,526,528

    hipLaunchKernelGGL(prep_all, dim3((3179520 + 255) / 256), dim3(256), 0, stream,
                       wDef, wOff, wFus, wdefMF, woffMF, wfusMF);
    hipLaunchKernelGGL(xt_build, dim3(64, 4, 12), dim3(256), 0, stream, in, XT);
    hipLaunchKernelGGL(corr_partial, dim3(64, 12, 4), dim3(256), 0, stream, in, corrP);
    hipLaunchKernelGGL(corr_reduce, dim3(64, 12), dim3(256), 0, stream, corrP, XT);
    hipLaunchKernelGGL(offconv_mfma, dim3(384), dim3(256), 0, stream, XT, woffMF, offB);
    hipLaunchKernelGGL(ft_build_y, dim3(64, 4, 4), dim3(256), 0, stream, in, FT);
    hipLaunchKernelGGL(deform_mfma, dim3(768), dim3(256), 0, stream, XT, offB, wdefMF, FT);
    hipLaunchKernelGGL(fusion_mfma, dim3(256), dim3(256), 0, stream, FT, wfusMF, out);
}

// Round 18
// 473.881 us; speedup vs baseline: 1.2252x; 1.2252x over previous
//
#include <hip/hip_runtime.h>

#define HH 64
#define WW 64
#define HW 4096
#define CC 256
#define BB 4
#define GG 4
#define NPAIR 3

typedef __attribute__((ext_vector_type(8))) short short8;
typedef __attribute__((ext_vector_type(4))) float f32x4;
typedef unsigned short ushort_t;

__device__ inline ushort_t f2bf(float x) {
    unsigned int u = __float_as_uint(x);
    unsigned int r = (u + 0x7fffu + ((u >> 16) & 1u)) >> 16;
    return (ushort_t)r;
}
__device__ inline float bflo(unsigned u) { return __uint_as_float(u << 16); }
__device__ inline float bfhi(unsigned u) { return __uint_as_float(u & 0xffff0000u); }

// ---------------- merged weight prep (wdef | woff | wfus) ----------------
__global__ void prep_all(const float* __restrict__ wd, const float* __restrict__ wo,
                         const float* __restrict__ wf, ushort_t* __restrict__ wdefMF,
                         ushort_t* __restrict__ woffMF, ushort_t* __restrict__ wfusMF) {
    int idx = blockIdx.x * 256 + threadIdx.x;
    if (idx < 589824) {  // wdef -> wdefMF[k][o][c]
        int k = idx >> 16;
        int rem = idx & 65535;
        int o = rem >> 8;
        int c = rem & 255;
        wdefMF[idx] = f2bf(wd[((size_t)(o * 256 + c)) * 9 + k]);
        return;
    }
    idx -= 589824;
    if (idx < 230400) {  // woff -> woffMF[k][80][320] zero-padded
        int k = idx / (80 * 320);
        int rem = idx % (80 * 320);
        int o = rem / 320;
        int ci = rem % 320;
        woffMF[idx] = (o < 72 && ci < 305) ? f2bf(wo[((size_t)o * 305 + ci) * 9 + k])
                                           : (ushort_t)0;
        return;
    }
    idx -= 230400;
    if (idx < 2359296) {  // wfus -> wfusMF[k][o][ci]
        int k = idx / (256 * 1024);
        int rem = idx % (256 * 1024);
        int o = rem / 1024;
        int ci = rem % 1024;
        wfusMF[idx] = f2bf(wf[((size_t)o * 1024 + ci) * 9 + k]);
    }
}

// ---------------- XT build ----------------
__global__ void __launch_bounds__(256) xt_build(const float* __restrict__ in,
                                                ushort_t* __restrict__ XT) {
    __shared__ ushort_t tileT[64][72];
    int hw0 = blockIdx.x * 64;
    int ct = blockIdx.y;
    int z = blockIdx.z;
    int pair = z >> 2, b = z & 3;
    int t = threadIdx.x;
    int cil = t >> 2, q = t & 3;
    const float* sp = in + ((size_t)(b * 4 + pair) * 256 + ct * 64 + cil) * HW + hw0 + q * 16;
#pragma unroll
    for (int i = 0; i < 16; ++i) tileT[q * 16 + i][cil] = f2bf(sp[i]);
    __syncthreads();
    int hwl = t >> 2;
    const uint4* tp = reinterpret_cast<const uint4*>(&tileT[hwl][q * 16]);
    uint4* op = reinterpret_cast<uint4*>(
        &XT[((size_t)z * HW + hw0 + hwl) * 320 + ct * 64 + q * 16]);
    op[0] = tp[0];
    op[1] = tp[1];
}

// ---------------- FT build (y part) ----------------
__global__ void __launch_bounds__(256) ft_build_y(const float* __restrict__ in,
                                                  ushort_t* __restrict__ FT) {
    __shared__ ushort_t tileT[64][72];
    int hw0 = blockIdx.x * 64;
    int ct = blockIdx.y;
    int b = blockIdx.z;
    int t = threadIdx.x;
    int cil = t >> 2, q = t & 3;
    const float* sp = in + ((size_t)(b * 4 + 3) * 256 + ct * 64 + cil) * HW + hw0 + q * 16;
#pragma unroll
    for (int i = 0; i < 16; ++i) tileT[q * 16 + i][cil] = f2bf(sp[i]);
    __syncthreads();
    int hwl = t >> 2;
    const uint4* tp = reinterpret_cast<const uint4*>(&tileT[hwl][q * 16]);
    uint4* op = reinterpret_cast<uint4*>(
        &FT[((size_t)b * HW + hw0 + hwl) * 1024 + 768 + ct * 64 + q * 16]);
    op[0] = tp[0];
    op[1] = tp[1];
}

// ---------------- correlation via MFMA (banded gram matrix) ----------------
// grid 768 = 8 XCD x 96 (z-local). Block (z,h): X1 = XT[z] row h (64 px x 256ch),
// per di: X2 = y row2 from FT cols 768.. ; band tiles tj in {ti-1,ti,ti+1};
// extraction straight from acc regs; pre-zero covers edges/pad.
__global__ void __launch_bounds__(256, 2) corr_mfma(ushort_t* __restrict__ XT,
                                                    const ushort_t* __restrict__ FT) {
    __shared__ ushort_t Al[64][264];
    __shared__ ushort_t Bl[64][264];
    int lin = (blockIdx.x & 7) * 96 + (blockIdx.x >> 3);
    int z = lin >> 6, h = lin & 63;
    int b = z & 3;
    int t = threadIdx.x;
    int ti = t >> 6;
    int l15 = t & 15, kq = (t >> 4) & 3;
    const ushort_t* x1 = XT + ((size_t)z * HW + h * 64) * 320;
    const ushort_t* yb = FT + (size_t)b * HW * 1024 + 768;

    // pre-zero corr cols 256..319 of this block's 64 pixels
    {
        int p = t >> 2, q = t & 3;
        ushort_t* xr = XT + ((size_t)z * HW + h * 64 + p) * 320 + 256 + q * 16;
        uint4 zz = make_uint4(0, 0, 0, 0);
        *reinterpret_cast<uint4*>(xr) = zz;
        *reinterpret_cast<uint4*>(xr + 8) = zz;
    }
    // stage A: 64 px x 256 ch
    for (int idx = t; idx < 2048; idx += 256) {
        int r = idx >> 5, q = idx & 31;
        *reinterpret_cast<uint4*>(&Al[r][q * 8]) =
            *reinterpret_cast<const uint4*>(x1 + (size_t)r * 320 + q * 8);
    }
    __syncthreads();

    int tj0 = max(ti - 1, 0), tj1 = min(ti + 1, 3);
#pragma unroll 1
    for (int di = 0; di < 7; ++di) {
        int row2 = h + 2 * (di - 3);
        bool vrow = (row2 >= 0) && (row2 < HH);
        if (vrow) {
            for (int idx = t; idx < 2048; idx += 256) {
                int r = idx >> 5, q = idx & 31;
                *reinterpret_cast<uint4*>(&Bl[r][q * 8]) =
                    *reinterpret_cast<const uint4*>(
                        yb + ((size_t)(row2 * 64 + r)) * 1024 + q * 8);
            }
        }
        __syncthreads();
        if (vrow) {
#pragma unroll 1
            for (int tj = tj0; tj <= tj1; ++tj) {
                f32x4 acc = (f32x4){0.f, 0.f, 0.f, 0.f};
#pragma unroll
                for (int cs = 0; cs < 8; ++cs) {
                    int c0 = cs * 32;
                    short8 a = *reinterpret_cast<const short8*>(&Al[ti * 16 + l15][c0 + kq * 8]);
                    short8 bb = *reinterpret_cast<const short8*>(&Bl[tj * 16 + l15][c0 + kq * 8]);
                    acc = __builtin_amdgcn_mfma_f32_16x16x32_bf16(a, bb, acc, 0, 0, 0);
                }
#pragma unroll
                for (int e = 0; e < 4; ++e) {
                    int row = ti * 16 + 4 * kq + e;
                    int col = tj * 16 + l15;
                    int d = col - row + 6;
                    if (d >= 0 && d <= 12 && !(d & 1)) {
                        XT[((size_t)z * HW + h * 64 + row) * 320 + 256 + di * 7 + (d >> 1)] =
                            f2bf(acc[e] * (1.f / 256.f));
                    }
                }
            }
        }
        __syncthreads();
    }
}

// ---------------- offset conv via MFMA bf16 (r14 best, unchanged) ----------------
__global__ void __launch_bounds__(256, 2) offconv_mfma(const ushort_t* __restrict__ XT,
                                                       const ushort_t* __restrict__ wmf,
                                                       float* __restrict__ off) {
    __shared__ ushort_t a_lds[9][80][40];
    __shared__ ushort_t b_hal[264][40];
    int lin = (blockIdx.x & 7) * 48 + (blockIdx.x >> 3);
    int z = lin >> 5;
    int n0t = lin & 31;
    int h0 = n0t * 2;
    int t = threadIdx.x;
    int wid = t >> 6;
    int lane = t & 63;
    int l15 = lane & 15;
    int kq = lane >> 4;
    const ushort_t* xtb = XT + (size_t)z * HW * 320;

    f32x4 acc[5][2];
#pragma unroll
    for (int m = 0; m < 5; ++m)
#pragma unroll
        for (int n = 0; n < 2; ++n) acc[m][n] = (f32x4){0.f, 0.f, 0.f, 0.f};

#pragma unroll 1
    for (int cs = 0; cs < 10; ++cs) {
        int ci0 = cs * 32;
        __syncthreads();
        for (int idx = t; idx < 264; idx += 256) {
            int r = idx / 66, c = idx - r * 66;
            int hP = h0 + r - 1, wP = c - 1;
            uint4* dst = reinterpret_cast<uint4*>(&b_hal[idx][0]);
            if (hP >= 0 && hP < HH && wP >= 0 && wP < WW) {
                const uint4* src = reinterpret_cast<const uint4*>(
                    xtb + (size_t)(hP * WW + wP) * 320 + ci0);
                dst[0] = src[0];
                dst[1] = src[1];
                dst[2] = src[2];
                dst[3] = src[3];
            } else {
                uint4 zz = make_uint4(0, 0, 0, 0);
                dst[0] = zz;
                dst[1] = zz;
                dst[2] = zz;
                dst[3] = zz;
            }
        }
        for (int idx = t; idx < 2880; idx += 256) {
            int tp = idx / 320;
            int rem = idx - tp * 320;
            int o = rem >> 2, q = rem & 3;
            *reinterpret_cast<uint4*>(&a_lds[tp][o][q * 8]) =
                *reinterpret_cast<const uint4*>(
                    wmf + ((size_t)tp * 80 + o) * 320 + ci0 + q * 8);
        }
        __syncthreads();
#pragma unroll 1
        for (int tap = 0; tap < 9; ++tap) {
            int kh = tap / 3, kw = tap - kh * 3;
            short8 af[5], bf[2];
#pragma unroll
            for (int m = 0; m < 5; ++m)
                af[m] = *reinterpret_cast<const short8*>(&a_lds[tap][m * 16 + l15][kq * 8]);
#pragma unroll
            for (int n = 0; n < 2; ++n) {
                int p = wid * 32 + n * 16 + l15;
                int pos = ((p >> 6) + kh) * 66 + (p & 63) + kw;
                bf[n] = *reinterpret_cast<const short8*>(&b_hal[pos][kq * 8]);
            }
#pragma unroll
            for (int m = 0; m < 5; ++m)
#pragma unroll
                for (int n = 0; n < 2; ++n)
                    acc[m][n] = __builtin_amdgcn_mfma_f32_16x16x32_bf16(af[m], bf[n],
                                                                        acc[m][n], 0, 0, 0);
        }
    }
    float* ob = off + (size_t)z * 72 * HW + h0 * 64 + wid * 32;
#pragma unroll
    for (int m = 0; m < 5; ++m)
#pragma unroll
        for (int n = 0; n < 2; ++n)
#pragma unroll
            for (int e = 0; e < 4; ++e) {
                int o_l = m * 16 + kq * 4 + e;
                if (o_l < 72) ob[(size_t)o_l * HW + n * 16 + l15] = acc[m][n][e];
            }
}

// ---------------- deformable conv via MFMA bf16 (r10 optimum, verbatim) ----------------
__global__ void __launch_bounds__(256, 3) deform_mfma(const ushort_t* __restrict__ XT,
                                                      const float* __restrict__ off,
                                                      const ushort_t* __restrict__ wmf,
                                                      ushort_t* __restrict__ FT) {
    __shared__ ushort_t b_lds[64][264];
    int u = blockIdx.x & 7, v = blockIdx.x >> 3;
    int lin = u * 96 + v;
    int z = lin >> 6, h = lin & 63;
    int b = z & 3, pair = z >> 2;

    const ushort_t* xtz = XT + (size_t)z * HW * 320;
    const float* offp = off + (size_t)z * 72 * HW;
    int tid = threadIdx.x;
    int lane = tid & 63;
    int g = tid >> 6;
    int l15 = tid & 15;
    int kq = (tid >> 4) & 3;

    f32x4 acc[4][4];
#pragma unroll
    for (int m = 0; m < 4; ++m)
#pragma unroll
        for (int n = 0; n < 4; ++n) acc[m][n] = (f32x4){0.f, 0.f, 0.f, 0.f};

    for (int k = 0; k < 9; ++k) {
        __syncthreads();
        {
            float oy = offp[(size_t)(g * 18 + k * 2 + 0) * HW + h * WW + lane];
            float ox = offp[(size_t)(g * 18 + k * 2 + 1) * HW + h * WW + lane];
            float py = (float)h + (float)(k / 3 - 1) + oy;
            float px = (float)lane + (float)(k % 3 - 1) + ox;
            float y0f = floorf(py), x0f = floorf(px);
            float fy = py - y0f, fx = px - x0f;
            int y0 = (int)y0f, x0 = (int)x0f;
            int y1 = y0 + 1, x1 = x0 + 1;
            bool vy0 = (y0 >= 0) && (y0 < HH);
            bool vy1 = (y1 >= 0) && (y1 < HH);
            bool vx0 = (x0 >= 0) && (x0 < WW);
            bool vx1 = (x1 >= 0) && (x1 < WW);
            float w00 = (1.f - fy) * (1.f - fx) * ((vy0 && vx0) ? 1.f : 0.f);
            float w01 = (1.f - fy) * fx * ((vy0 && vx1) ? 1.f : 0.f);
            float w10 = fy * (1.f - fx) * ((vy1 && vx0) ? 1.f : 0.f);
            float w11 = fy * fx * ((vy1 && vx1) ? 1.f : 0.f);
            int cy0 = min(max(y0, 0), HH - 1), cy1 = min(max(y1, 0), HH - 1);
            int cx0 = min(max(x0, 0), WW - 1), cx1 = min(max(x1, 0), WW - 1);
            const ushort_t* p00 = xtz + (size_t)(cy0 * WW + cx0) * 320 + g * 64;
            const ushort_t* p01 = xtz + (size_t)(cy0 * WW + cx1) * 320 + g * 64;
            const ushort_t* p10 = xtz + (size_t)(cy1 * WW + cx0) * 320 + g * 64;
            const ushort_t* p11 = xtz + (size_t)(cy1 * WW + cx1) * 320 + g * 64;
#pragma unroll
            for (int c0 = 0; c0 < 64; c0 += 8) {
                uint4 a00 = *reinterpret_cast<const uint4*>(p00 + c0);
                uint4 a01 = *reinterpret_cast<const uint4*>(p01 + c0);
                uint4 a10 = *reinterpret_cast<const uint4*>(p10 + c0);
                uint4 a11 = *reinterpret_cast<const uint4*>(p11 + c0);
                unsigned pw[4];
                const unsigned* u00 = &a00.x;
                const unsigned* u01 = &a01.x;
                const unsigned* u10 = &a10.x;
                const unsigned* u11 = &a11.x;
#pragma unroll
                for (int q = 0; q < 4; ++q) {
                    float s0 = w00 * bflo(u00[q]) + w01 * bflo(u01[q]) +
                               w10 * bflo(u10[q]) + w11 * bflo(u11[q]);
                    float s1 = w00 * bfhi(u00[q]) + w01 * bfhi(u01[q]) +
                               w10 * bfhi(u10[q]) + w11 * bfhi(u11[q]);
                    pw[q] = (unsigned)f2bf(s0) | ((unsigned)f2bf(s1) << 16);
                }
                *reinterpret_cast<uint4*>(&b_lds[lane][g * 64 + c0]) =
                    make_uint4(pw[0], pw[1], pw[2], pw[3]);
            }
        }
        __syncthreads();
        const ushort_t* wkbase = wmf + (size_t)k * 65536 + (size_t)(g * 64) * 256;
#pragma unroll 1
        for (int cs = 0; cs < 8; ++cs) {
            int c0 = cs * 32;
            short8 bfr[4], afr[4];
#pragma unroll
            for (int n = 0; n < 4; ++n)
                bfr[n] = *reinterpret_cast<const short8*>(&b_lds[n * 16 + l15][c0 + kq * 8]);
#pragma unroll
            for (int m = 0; m < 4; ++m)
                afr[m] = *reinterpret_cast<const short8*>(
                    wkbase + (size_t)(m * 16 + l15) * 256 + c0 + kq * 8);
#pragma unroll
            for (int m = 0; m < 4; ++m)
#pragma unroll
                for (int n = 0; n < 4; ++n)
                    acc[m][n] = __builtin_amdgcn_mfma_f32_16x16x32_bf16(afr[m], bfr[n],
                                                                        acc[m][n], 0, 0, 0);
        }
    }
    __syncthreads();
#pragma unroll
    for (int m = 0; m < 4; ++m)
#pragma unroll
        for (int n = 0; n < 4; ++n) {
            unsigned lo = (unsigned)f2bf(acc[m][n][0]) | ((unsigned)f2bf(acc[m][n][1]) << 16);
            unsigned hi = (unsigned)f2bf(acc[m][n][2]) | ((unsigned)f2bf(acc[m][n][3]) << 16);
            uint2 vv = make_uint2(lo, hi);
            *reinterpret_cast<uint2*>(&b_lds[n * 16 + l15][g * 64 + m * 16 + kq * 4]) = vv;
        }
    __syncthreads();
    int wout = tid >> 2, ch = tid & 3;
    ushort_t* dst = FT + ((size_t)b * HW + h * 64 + wout) * 1024 + pair * 256 + ch * 64;
    const ushort_t* srcl = &b_lds[wout][ch * 64];
#pragma unroll
    for (int i = 0; i < 8; ++i) {
        uint4 vv = *reinterpret_cast<const uint4*>(srcl + i * 8);
        *reinterpret_cast<uint4*>(dst + i * 8) = vv;
    }
}

// ---------------- fusion conv via MFMA bf16 (64o x 128hw, r14/r16 best) ----------------
__global__ void __launch_bounds__(256, 2) fusion_mfma(const ushort_t* __restrict__ FT,
                                                      const ushort_t* __restrict__ wmf,
                                                      float* __restrict__ out) {
    __shared__ ushort_t a_lds[9][64][40];
    __shared__ ushort_t b_hal[264][40];
    int lin = ((blockIdx.x & 7) << 6) | (blockIdx.x >> 3);
    int ot = lin & 3;
    int g2 = lin >> 2;
    int n0t = g2 & 31;
    int b = g2 >> 5;
    int o0 = ot * 64;
    int h0 = n0t * 2;
    int t = threadIdx.x;
    int wid = t >> 6;
    int lane = t & 63;
    int l15 = lane & 15;
    int kq = lane >> 4;
    const ushort_t* ftb = FT + (size_t)b * HW * 1024;

    f32x4 acc[4][2];
#pragma unroll
    for (int fm = 0; fm < 4; ++fm)
#pragma unroll
        for (int fn = 0; fn < 2; ++fn) acc[fm][fn] = (f32x4){0.f, 0.f, 0.f, 0.f};

#pragma unroll 1
    for (int cs = 0; cs < 32; ++cs) {
        int ci0 = cs * 32;
        __syncthreads();
        for (int idx = t; idx < 264; idx += 256) {
            int r = idx / 66, c = idx - r * 66;
            int hP = h0 + r - 1, wP = c - 1;
            uint4* dst = reinterpret_cast<uint4*>(&b_hal[idx][0]);
            if (hP >= 0 && hP < HH && wP >= 0 && wP < WW) {
                const uint4* src = reinterpret_cast<const uint4*>(
                    ftb + (size_t)(hP * WW + wP) * 1024 + ci0);
                dst[0] = src[0];
                dst[1] = src[1];
                dst[2] = src[2];
                dst[3] = src[3];
            } else {
                uint4 zz = make_uint4(0, 0, 0, 0);
                dst[0] = zz;
                dst[1] = zz;
                dst[2] = zz;
                dst[3] = zz;
            }
        }
        for (int idx = t; idx < 2304; idx += 256) {
            int tp = idx >> 8;
            int rem = idx & 255;
            int o = rem >> 2, q = rem & 3;
            *reinterpret_cast<uint4*>(&a_lds[tp][o][q * 8]) =
                *reinterpret_cast<const uint4*>(
                    wmf + ((size_t)(tp * 256 + o0 + o) << 10) + ci0 + q * 8);
        }
        __syncthreads();
#pragma unroll 1
        for (int tap = 0; tap < 9; ++tap) {
            int kh = tap / 3, kw = tap - kh * 3;
            short8 af[4], bf[2];
#pragma unroll
            for (int m = 0; m < 4; ++m)
                af[m] = *reinterpret_cast<const short8*>(&a_lds[tap][m * 16 + l15][kq * 8]);
#pragma unroll
            for (int n = 0; n < 2; ++n) {
                int p = wid * 32 + n * 16 + l15;
                int pos = ((p >> 6) + kh) * 66 + (p & 63) + kw;
                bf[n] = *reinterpret_cast<const short8*>(&b_hal[pos][kq * 8]);
            }
#pragma unroll
            for (int m = 0; m < 4; ++m)
#pragma unroll
                for (int n = 0; n < 2; ++n)
                    acc[m][n] = __builtin_amdgcn_mfma_f32_16x16x32_bf16(af[m], bf[n],
                                                                        acc[m][n], 0, 0, 0);
        }
    }
    float* ob = out + ((size_t)b * 256 + o0) * HW + h0 * 64 + wid * 32;
#pragma unroll
    for (int fm = 0; fm < 4; ++fm)
#pragma unroll
        for (int fn = 0; fn < 2; ++fn)
#pragma unroll
            for (int e = 0; e < 4; ++e) {
                int o_l = fm * 16 + 4 * kq + e;
                ob[(size_t)o_l * HW + fn * 16 + l15] = acc[fm][fn][e];
            }
}

extern "C" void kernel_launch(void* const* d_in, const int* in_sizes, int n_in,
                              void* d_out, int out_size, void* d_ws, size_t ws_size,
                              hipStream_t stream) {
    const float* in   = (const float*)d_in[0];   // [16,256,64,64]
    const float* wOff = (const float*)d_in[1];   // [72,305,3,3]
    const float* wDef = (const float*)d_in[2];   // [256,256,3,3]
    const float* wFus = (const float*)d_in[3];   // [256,1024,3,3]
    float* out = (float*)d_out;                  // [4,256,64,64]
    char* base = (char*)d_ws;

    ushort_t* XT     = (ushort_t*)base;                 // 31,457,280 B
    ushort_t* FT     = (ushort_t*)(base + 31457280);    // 33,554,432 B -> 65,011,712
    float* offB      = (float*)(base + 65011712);       // 14,155,776 B -> 79,167,488
    ushort_t* wdefMF = (ushort_t*)(base + 79167488);    //  1,179,648 B -> 80,347,136
    ushort_t* woffMF = (ushort_t*)(base + 80347136);    //    460,800 B -> 80,807,936
    ushort_t* wfusMF = (ushort_t*)(base + 80807936);    //  4,718,592 B -> 85,526,528

    hipLaunchKernelGGL(prep_all, dim3((3179520 + 255) / 256), dim3(256), 0, stream,
                       wDef, wOff, wFus, wdefMF, woffMF, wfusMF);
    hipLaunchKernelGGL(xt_build, dim3(64, 4, 12), dim3(256), 0, stream, in, XT);
    hipLaunchKernelGGL(ft_build_y, dim3(64, 4, 4), dim3(256), 0, stream, in, FT);
    hipLaunchKernelGGL(corr_mfma, dim3(768), dim3(256), 0, stream, XT, FT);
    hipLaunchKernelGGL(offconv_mfma, dim3(384), dim3(256), 0, stream, XT, woffMF, offB);
    hipLaunchKernelGGL(deform_mfma, dim3(768), dim3(256), 0, stream, XT, offB, wdefMF, FT);
    hipLaunchKernelGGL(fusion_mfma, dim3(512), dim3(256), 0, stream, FT, wfusMF, out);
}